// Round 7
// baseline (626.191 us; speedup 1.0000x reference)
//
#include <hip/hip_runtime.h>
#include <math.h>

// Problem constants
#define Bq 4
#define Lq 2048
#define BLq 8192          // B*L
#define DMq 128           // d_model
#define DIq 256           // d_inner
#define DSq 16            // d_state
#define NC2 32            // scan chunks
#define TC2 64            // chunk length (NC2*TC2 == Lq)

typedef short short8 __attribute__((ext_vector_type(8)));
typedef float f32x4 __attribute__((ext_vector_type(4)));

__device__ __forceinline__ float siluf(float x){ return x / (1.f + expf(-x)); }
__device__ __forceinline__ float softplusf(float x){
  return (x > 0.f) ? (x + log1pf(expf(-x))) : log1pf(expf(x));
}
// bf16 round-to-nearest-even via bit ops (no API-version dependence)
__device__ __forceinline__ unsigned short f2bf(float v){
  unsigned int u = __float_as_uint(v);
  return (unsigned short)((u + 0x7FFFu + ((u >> 16) & 1u)) >> 16);
}
__device__ __forceinline__ float bf2f(unsigned short h){
  return __uint_as_float(((unsigned int)h) << 16);
}

// split fp32 array -> bf16 hi/lo pair (for weights; once per call)
__global__ __launch_bounds__(256) void k_split(const float* __restrict__ in,
    unsigned short* __restrict__ hi, unsigned short* __restrict__ lo, int n){
  int i = blockIdx.x*256 + threadIdx.x;
  if (i < n){
    float v = in[i];
    unsigned short h = f2bf(v);
    hi[i] = h;
    lo[i] = f2bf(v - bf2f(h));
  }
}

// h[bl,e] = x@W_emb + b ; also emit bf16 hi/lo split for the MFMA gemm
__global__ __launch_bounds__(128) void k_embed(const float* __restrict__ x,
    const float* __restrict__ W, const float* __restrict__ bb, float* __restrict__ h,
    unsigned short* __restrict__ hhi, unsigned short* __restrict__ hlo){
  int bl = blockIdx.x; int e = threadIdx.x;
  __shared__ float xs[64];
  if (e < 64) xs[e] = x[(size_t)bl*64 + e];
  __syncthreads();
  float acc = bb[e];
  #pragma unroll
  for (int k=0;k<64;k++) acc = fmaf(xs[k], W[k*128 + e], acc);
  size_t idx = (size_t)bl*128 + e;
  h[idx] = acc;
  unsigned short hb = f2bf(acc);
  hhi[idx] = hb;
  hlo[idx] = f2bf(acc - bf2f(hb));
}

// C[M,N] = A[M,K] @ W[N,K]^T via bf16x3 MFMA (hi*hi + hi*lo + lo*hi).
// Block 256 thr = 4 waves (2x2); block tile 128x64; wave tile 64x32 (4x2 16x16 frags).
__global__ __launch_bounds__(256) void k_mfma_bt(
    const unsigned short* __restrict__ Ahi, const unsigned short* __restrict__ Alo,
    const unsigned short* __restrict__ Whi, const unsigned short* __restrict__ Wlo,
    float* __restrict__ C, unsigned short* __restrict__ Chi, unsigned short* __restrict__ Clo,
    int M, int N, int K){
  const int tid = threadIdx.x;
  const int l = tid & 63, w = tid >> 6;
  const int wr = w >> 1, wc = w & 1;
  const int l15 = l & 15;
  const int ko = (l >> 4) << 3;          // k-offset 0/8/16/24 (same map for A and W)
  const int m0 = blockIdx.x << 7;
  const int n0 = blockIdx.y << 6;
  const int arow = m0 + wr*64 + l15;
  const int wrow = n0 + wc*32 + l15;
  f32x4 acc[4][2] = {};
  for (int kk = 0; kk < K; kk += 32){
    short8 ah[4], al[4], wh[2], wl[2];
    #pragma unroll
    for (int t=0;t<4;t++){
      size_t off = (size_t)(arow + t*16)*K + kk + ko;
      ah[t] = *(const short8*)(Ahi + off);
      al[t] = *(const short8*)(Alo + off);
    }
    #pragma unroll
    for (int s=0;s<2;s++){
      size_t off = (size_t)(wrow + s*16)*K + kk + ko;
      wh[s] = *(const short8*)(Whi + off);
      wl[s] = *(const short8*)(Wlo + off);
    }
    #pragma unroll
    for (int t=0;t<4;t++){
      #pragma unroll
      for (int s=0;s<2;s++){
        acc[t][s] = __builtin_amdgcn_mfma_f32_16x16x32_bf16(ah[t], wh[s], acc[t][s], 0,0,0);
        acc[t][s] = __builtin_amdgcn_mfma_f32_16x16x32_bf16(ah[t], wl[s], acc[t][s], 0,0,0);
        acc[t][s] = __builtin_amdgcn_mfma_f32_16x16x32_bf16(al[t], wh[s], acc[t][s], 0,0,0);
      }
    }
  }
  const int r0 = (l >> 4) << 2;          // C/D: col=lane&15, row=(lane>>4)*4+r (m89-verified)
  #pragma unroll
  for (int t=0;t<4;t++){
    #pragma unroll
    for (int s=0;s<2;s++){
      #pragma unroll
      for (int r=0;r<4;r++){
        int row = m0 + wr*64 + t*16 + r0 + r;
        int col = n0 + wc*32 + s*16 + l15;
        size_t idx = (size_t)row*N + col;
        float v = acc[t][s][r];
        C[idx] = v;
        if (Chi){
          unsigned short hb = f2bf(v);
          Chi[idx] = hb;
          Clo[idx] = f2bf(v - bf2f(hb));
        }
      }
    }
  }
}

// causal depthwise conv (D_CONV=4) over u-half of xz, then SiLU -> u
__global__ __launch_bounds__(256) void k_conv(const float* __restrict__ xz,
    const float* __restrict__ cw, const float* __restrict__ cb, float* __restrict__ u){
  int bl = blockIdx.x; int l = bl & 2047; int d = threadIdx.x;
  float4 w = *(const float4*)(cw + d*4);
  float wv[4] = {w.x, w.y, w.z, w.w};
  const float* base = xz + (size_t)bl*512 + d;
  float acc = cb[d];
  #pragma unroll
  for (int j=0;j<4;j++){
    if (l-3+j >= 0) acc = fmaf(base[(j-3)*512], wv[j], acc);
  }
  u[(size_t)bl*256 + d] = siluf(acc);
}

// pad xp_w [4][40][256] -> xdp [4][64][256] (rows 40..63 zero). grid 256, blk 256.
__global__ __launch_bounds__(256) void k_padw(const float* __restrict__ xpw,
    float* __restrict__ xdp){
  int blk = blockIdx.x; int layer = blk >> 6, e = blk & 63;
  int tid = threadIdx.x;
  float v = 0.f;
  if (e < 40) v = xpw[((size_t)layer*40 + e)*256 + tid];
  xdp[((size_t)layer*64 + e)*256 + tid] = v;
}

// xd[8192x64] = u[8192x256] @ xdp[64x256]^T. BM=32,BN=64,BK=32, 256 blocks.
__global__ __launch_bounds__(256) void k_xg(const float* __restrict__ u,
    const float* __restrict__ xdp, float* __restrict__ xd){
  __shared__ float As[32][34];
  __shared__ float Ws[32][68];
  const int tid = threadIdx.x;
  const int m0 = blockIdx.x << 5;
  const int tm = tid & 15, tn = tid >> 4;
  const int r = tid >> 3, c4 = (tid & 7) << 2;
  float acc[2][4] = {};
  for (int k0=0;k0<256;k0+=32){
    float4 av = *(const float4*)(u + (size_t)(m0+r)*256 + k0 + c4);
    As[c4+0][r]=av.x; As[c4+1][r]=av.y; As[c4+2][r]=av.z; As[c4+3][r]=av.w;
    #pragma unroll
    for (int p=0;p<2;p++){
      int q = tid + p*256;
      int n = q >> 3, wc = (q & 7) << 2;
      float4 wv = *(const float4*)(xdp + (size_t)n*256 + k0 + wc);
      Ws[wc+0][n]=wv.x; Ws[wc+1][n]=wv.y; Ws[wc+2][n]=wv.z; Ws[wc+3][n]=wv.w;
    }
    __syncthreads();
    #pragma unroll
    for (int k=0;k<32;k++){
      float2 a = *(const float2*)&As[k][tm<<1];
      float4 w = *(const float4*)&Ws[k][tn<<2];
      acc[0][0]=fmaf(a.x,w.x,acc[0][0]); acc[0][1]=fmaf(a.x,w.y,acc[0][1]);
      acc[0][2]=fmaf(a.x,w.z,acc[0][2]); acc[0][3]=fmaf(a.x,w.w,acc[0][3]);
      acc[1][0]=fmaf(a.y,w.x,acc[1][0]); acc[1][1]=fmaf(a.y,w.y,acc[1][1]);
      acc[1][2]=fmaf(a.y,w.z,acc[1][2]); acc[1][3]=fmaf(a.y,w.w,acc[1][3]);
    }
    __syncthreads();
  }
  #pragma unroll
  for (int i=0;i<2;i++){
    *(float4*)(xd + (size_t)(m0 + (tm<<1) + i)*64 + (tn<<2)) =
        make_float4(acc[i][0],acc[i][1],acc[i][2],acc[i][3]);
  }
}

// delta = softplus(xd[:, :8] @ dtw^T + dtb) -> dlt[8192x256]; bc = xd[:, 8:40]
__global__ __launch_bounds__(256) void k_delta(const float* __restrict__ xd,
    const float* __restrict__ dtw, const float* __restrict__ dtb,
    float* __restrict__ dlt, float* __restrict__ bc){
  __shared__ float wt[8][256];
  __shared__ float xds[32][8];
  const int tid = threadIdx.x;
  const int row0 = blockIdx.x << 5;
  {
    float4 w0 = *(const float4*)(dtw + tid*8);
    float4 w1 = *(const float4*)(dtw + tid*8 + 4);
    wt[0][tid]=w0.x; wt[1][tid]=w0.y; wt[2][tid]=w0.z; wt[3][tid]=w0.w;
    wt[4][tid]=w1.x; wt[5][tid]=w1.y; wt[6][tid]=w1.z; wt[7][tid]=w1.w;
  }
  if (tid < 64){
    int rr = tid >> 1, cc = (tid & 1) << 2;
    *(float4*)&xds[rr][cc] = *(const float4*)(xd + (size_t)(row0+rr)*64 + cc);
  }
  __syncthreads();
  float bias = dtb[tid];
  for (int rr=0; rr<32; ++rr){
    float acc = bias;
    #pragma unroll
    for (int j=0;j<8;j++) acc = fmaf(xds[rr][j], wt[j][tid], acc);
    dlt[(size_t)(row0+rr)*256 + tid] = softplusf(acc);
  }
  #pragma unroll
  for (int k=0;k<4;k++){
    int idx = k*256 + tid;
    int rr = idx >> 5, cc = idx & 31;
    bc[(size_t)(row0+rr)*32 + cc] = xd[(size_t)(row0+rr)*64 + 8 + cc];
  }
}

// ---------------- scan: LDS-staged, thread = (d, 4 n-states) ----------------
__global__ __launch_bounds__(128) void k_scan_a2(const float* __restrict__ dlt,
    const float* __restrict__ u, const float* __restrict__ bc,
    const float* __restrict__ alog, float* __restrict__ sf, float* __restrict__ sd){
  __shared__ float ds_[TC2*32], us_[TC2*32], bs_[TC2*16];
  const int tid = threadIdx.x;
  const int c = blockIdx.x, dg = blockIdx.y, b = blockIdx.z;
  const size_t row0 = (size_t)b*Lq + (size_t)c*TC2;
  {
    const float* dbase = dlt + row0*256 + dg*32;
    const float* ubase = u   + row0*256 + dg*32;
    #pragma unroll
    for (int k=0;k<4;k++){
      int q = tid + k*128;
      int r = q >> 3, c4 = (q & 7) << 2;
      *(float4*)&ds_[r*32 + c4] = *(const float4*)(dbase + (size_t)r*256 + c4);
      *(float4*)&us_[r*32 + c4] = *(const float4*)(ubase + (size_t)r*256 + c4);
    }
    const float* bbase = bc + row0*32;
    #pragma unroll
    for (int k=0;k<2;k++){
      int q = tid + k*128;
      int r = q >> 2, c4 = (q & 3) << 2;
      *(float4*)&bs_[r*16 + c4] = *(const float4*)(bbase + (size_t)r*32 + c4);
    }
  }
  __syncthreads();
  const int lane = tid & 63, w = tid >> 6;
  const int dloc = w*16 + (lane & 15);
  const int nq = (lane >> 4) & 3;
  const int d = dg*32 + dloc;
  float4 al = *(const float4*)(alog + d*16 + nq*4);
  float Av0 = -expf(al.x), Av1 = -expf(al.y), Av2 = -expf(al.z), Av3 = -expf(al.w);
  float s0=0.f,s1=0.f,s2=0.f,s3=0.f, sdl=0.f;
  for (int t=0;t<TC2;t++){
    float de = ds_[t*32 + dloc];
    float uu = us_[t*32 + dloc];
    float du = de*uu;
    float4 Bv = *(const float4*)&bs_[t*16 + (nq<<2)];
    s0 = fmaf(expf(de*Av0), s0, du*Bv.x);
    s1 = fmaf(expf(de*Av1), s1, du*Bv.y);
    s2 = fmaf(expf(de*Av2), s2, du*Bv.z);
    s3 = fmaf(expf(de*Av3), s3, du*Bv.w);
    sdl += de;
  }
  size_t idx = ((size_t)b*NC2 + c)*256 + d;
  *(float4*)(sf + idx*16 + (nq<<2)) = make_float4(s0,s1,s2,s3);
  if (nq==0) sd[idx] = sdl;
}

__global__ __launch_bounds__(256) void k_scan_b2(const float* __restrict__ sf,
    const float* __restrict__ sd, const float* __restrict__ alog, float* __restrict__ si){
  int b = blockIdx.x >> 4, dg = blockIdx.x & 15;
  int tid = threadIdx.x; int n = tid & 15, dl = tid >> 4; int d = dg*16 + dl;
  float Av = -expf(alog[d*16+n]);
  float s = 0.f;
  for (int c=0;c<NC2;c++){
    size_t idx = ((size_t)b*NC2 + c)*256 + d;
    si[idx*16+n] = s;
    s = sf[idx*16+n] + expf(Av * sd[idx]) * s;
  }
}

// scan pass C: fused epilogue y=(sum_n sC + uD)*silu(z), emitted as bf16 hi/lo
__global__ __launch_bounds__(128) void k_scan_c2(const float* __restrict__ dlt,
    const float* __restrict__ u, const float* __restrict__ bc,
    const float* __restrict__ xz, const float* __restrict__ si,
    const float* __restrict__ alog, const float* __restrict__ dsk,
    unsigned short* __restrict__ yhi, unsigned short* __restrict__ ylo){
  __shared__ float ds_[TC2*32], us_[TC2*32], bcs_[TC2*32], zs_[TC2*32], ys_[TC2*32];
  const int tid = threadIdx.x;
  const int c = blockIdx.x, dg = blockIdx.y, b = blockIdx.z;
  const size_t row0 = (size_t)b*Lq + (size_t)c*TC2;
  {
    const float* dbase = dlt + row0*256 + dg*32;
    const float* ubase = u   + row0*256 + dg*32;
    const float* zbase = xz  + row0*512 + 256 + dg*32;
    const float* bbase = bc  + row0*32;
    #pragma unroll
    for (int k=0;k<4;k++){
      int q = tid + k*128;
      int r = q >> 3, c4 = (q & 7) << 2;
      *(float4*)&ds_[r*32 + c4]  = *(const float4*)(dbase + (size_t)r*256 + c4);
      *(float4*)&us_[r*32 + c4]  = *(const float4*)(ubase + (size_t)r*256 + c4);
      *(float4*)&zs_[r*32 + c4]  = *(const float4*)(zbase + (size_t)r*512 + c4);
      *(float4*)&bcs_[r*32 + c4] = *(const float4*)(bbase + (size_t)r*32  + c4);
    }
  }
  __syncthreads();
  const int lane = tid & 63, w = tid >> 6;
  const int dloc = w*16 + (lane & 15);
  const int nq = (lane >> 4) & 3;
  const int d = dg*32 + dloc;
  float4 al = *(const float4*)(alog + d*16 + (nq<<2));
  float Av0 = -expf(al.x), Av1 = -expf(al.y), Av2 = -expf(al.z), Av3 = -expf(al.w);
  float Dv = dsk[d];
  size_t idx = ((size_t)b*NC2 + c)*256 + d;
  float4 sv = *(const float4*)(si + idx*16 + (nq<<2));
  float s0 = sv.x, s1 = sv.y, s2 = sv.z, s3 = sv.w;
  for (int t=0;t<TC2;t++){
    float de = ds_[t*32 + dloc];
    float uu = us_[t*32 + dloc];
    float du = de*uu;
    float4 Bv = *(const float4*)&bcs_[t*32 + (nq<<2)];
    float4 Cv = *(const float4*)&bcs_[t*32 + 16 + (nq<<2)];
    s0 = fmaf(expf(de*Av0), s0, du*Bv.x);
    s1 = fmaf(expf(de*Av1), s1, du*Bv.y);
    s2 = fmaf(expf(de*Av2), s2, du*Bv.z);
    s3 = fmaf(expf(de*Av3), s3, du*Bv.w);
    float py = s0*Cv.x + s1*Cv.y + s2*Cv.z + s3*Cv.w;
    py += __shfl_xor(py, 16);
    py += __shfl_xor(py, 32);
    if (nq==0){
      float zz = zs_[t*32 + dloc];
      ys_[t*32 + dloc] = fmaf(uu, Dv, py) * siluf(zz);
    }
  }
  __syncthreads();
  {
    unsigned short* yh = yhi + row0*256 + dg*32;
    unsigned short* yl = ylo + row0*256 + dg*32;
    #pragma unroll
    for (int k=0;k<4;k++){
      int q = tid + k*128;
      int r = q >> 3, c4 = (q & 7) << 2;
      float4 v = *(const float4*)&ys_[r*32 + c4];
      ushort4 h4, l4;
      h4.x = f2bf(v.x); l4.x = f2bf(v.x - bf2f(h4.x));
      h4.y = f2bf(v.y); l4.y = f2bf(v.y - bf2f(h4.y));
      h4.z = f2bf(v.z); l4.z = f2bf(v.z - bf2f(h4.z));
      h4.w = f2bf(v.w); l4.w = f2bf(v.w - bf2f(h4.w));
      *(ushort4*)(yh + (size_t)r*256 + c4) = h4;
      *(ushort4*)(yl + (size_t)r*256 + c4) = l4;
    }
  }
}

// mean over L then latent GEMV: out[b,:] = pooled @ W_lat + b_lat
__global__ __launch_bounds__(1024) void k_pool(const float* __restrict__ h,
    const float* __restrict__ Wl, const float* __restrict__ bl_, float* __restrict__ out){
  int b = blockIdx.x; int tid = threadIdx.x;
  int e = tid & 127, st = tid >> 7;
  float s = 0.f;
  for (int l = st*256; l < st*256 + 256; ++l) s += h[((size_t)b*2048 + l)*128 + e];
  __shared__ float part[8][128];
  __shared__ float pooled[128];
  part[st][e] = s;
  __syncthreads();
  if (tid < 128){
    float tot = 0.f;
    #pragma unroll
    for (int j=0;j<8;j++) tot += part[j][tid];
    pooled[tid] = tot * (1.f/2048.f);
  }
  __syncthreads();
  if (tid < 128){
    float acc = bl_[tid];
    for (int e2=0;e2<128;e2++) acc = fmaf(pooled[e2], Wl[e2*128 + tid], acc);
    out[b*128 + tid] = acc;
  }
}

extern "C" void kernel_launch(void* const* d_in, const int* in_sizes, int n_in,
                              void* d_out, int out_size, void* d_ws, size_t ws_size,
                              hipStream_t stream){
  const float* x    = (const float*)d_in[0];
  const float* Wem  = (const float*)d_in[1];
  const float* bem  = (const float*)d_in[2];
  const float* inw  = (const float*)d_in[3];
  const float* cw   = (const float*)d_in[4];
  const float* cb   = (const float*)d_in[5];
  const float* xpw  = (const float*)d_in[6];
  const float* dtw  = (const float*)d_in[7];
  const float* dtb  = (const float*)d_in[8];
  const float* alog = (const float*)d_in[9];
  const float* dsk  = (const float*)d_in[10];
  const float* outw = (const float*)d_in[11];
  const float* Wl   = (const float*)d_in[12];
  const float* bl_  = (const float*)d_in[13];
  float* out = (float*)d_out;

  float* p  = (float*)d_ws;
  float* h  = p;  p += (size_t)BLq*128;
  float* xz = p;  p += (size_t)BLq*512;
  float* u  = p;  p += (size_t)BLq*256;
  float* dl = p;  p += (size_t)BLq*256;
  float* bc = p;  p += (size_t)BLq*32;
  float* sf = p;  p += (size_t)Bq*NC2*256*16;
  float* sd = p;  p += (size_t)Bq*NC2*256;
  float* si = p;  p += (size_t)Bq*NC2*256*16;
  float* xdp= p;  p += (size_t)4*64*256;
  float* xd = p;  p += (size_t)BLq*64;
  unsigned short* q = (unsigned short*)p;
  unsigned short* wihi = q; q += (size_t)4*512*128;
  unsigned short* wilo = q; q += (size_t)4*512*128;
  unsigned short* wohi = q; q += (size_t)4*128*256;
  unsigned short* wolo = q; q += (size_t)4*128*256;
  unsigned short* hhi  = q; q += (size_t)BLq*128;
  unsigned short* hlo  = q; q += (size_t)BLq*128;
  unsigned short* yhi  = q; q += (size_t)BLq*256;
  unsigned short* ylo  = q; q += (size_t)BLq*256;

  k_split<<<1024, 256, 0, stream>>>(inw, wihi, wilo, 4*512*128);
  k_split<<<512, 256, 0, stream>>>(outw, wohi, wolo, 4*128*256);
  k_padw<<<256, 256, 0, stream>>>(xpw, xdp);
  k_embed<<<BLq, 128, 0, stream>>>(x, Wem, bem, h, hhi, hlo);
  for (int layer=0; layer<4; ++layer){
    k_mfma_bt<<<dim3(64,8), 256, 0, stream>>>(hhi, hlo,
        wihi + (size_t)layer*512*128, wilo + (size_t)layer*512*128,
        xz, nullptr, nullptr, BLq, 512, 128);
    k_conv<<<BLq, 256, 0, stream>>>(xz, cw + (size_t)layer*256*4, cb + (size_t)layer*256, u);
    k_xg<<<256, 256, 0, stream>>>(u, xdp + (size_t)layer*64*256, xd);
    k_delta<<<256, 256, 0, stream>>>(xd, dtw + (size_t)layer*256*8, dtb + (size_t)layer*256,
                                     dl, bc);
    k_scan_a2<<<dim3(NC2,8,Bq), 128, 0, stream>>>(dl, u, bc, alog + (size_t)layer*4096, sf, sd);
    k_scan_b2<<<64, 256, 0, stream>>>(sf, sd, alog + (size_t)layer*4096, si);
    k_scan_c2<<<dim3(NC2,8,Bq), 128, 0, stream>>>(dl, u, bc, xz, si, alog + (size_t)layer*4096,
                                                  dsk + (size_t)layer*256, yhi, ylo);
    k_mfma_bt<<<dim3(64,2), 256, 0, stream>>>(yhi, ylo,
        wohi + (size_t)layer*128*256, wolo + (size_t)layer*128*256,
        h, hhi, hlo, BLq, 128, 256);
  }
  k_pool<<<Bq, 1024, 0, stream>>>(h, Wl, bl_, out);
}

// Round 8
// 545.828 us; speedup vs baseline: 1.1472x; 1.1472x over previous
//
#include <hip/hip_runtime.h>
#include <math.h>

// Problem constants
#define Bq 4
#define Lq 2048
#define BLq 8192          // B*L
#define DMq 128           // d_model
#define DIq 256           // d_inner
#define DSq 16            // d_state
#define NC2 32            // scan chunks
#define TC2 64            // chunk length (NC2*TC2 == Lq)

typedef short short8 __attribute__((ext_vector_type(8)));
typedef float f32x4 __attribute__((ext_vector_type(4)));

__device__ __forceinline__ float siluf(float x){ return x / (1.f + expf(-x)); }
__device__ __forceinline__ float softplusf(float x){
  return (x > 0.f) ? (x + log1pf(expf(-x))) : log1pf(expf(x));
}
__device__ __forceinline__ unsigned short f2bf(float v){
  unsigned int u = __float_as_uint(v);
  return (unsigned short)((u + 0x7FFFu + ((u >> 16) & 1u)) >> 16);
}
__device__ __forceinline__ float bf2f(unsigned short h){
  return __uint_as_float(((unsigned int)h) << 16);
}

// split fp32 array -> bf16 hi/lo pair (weights; once per call)
__global__ __launch_bounds__(256) void k_split(const float* __restrict__ in,
    unsigned short* __restrict__ hi, unsigned short* __restrict__ lo, int n){
  int i = blockIdx.x*256 + threadIdx.x;
  if (i < n){
    float v = in[i];
    unsigned short h = f2bf(v);
    hi[i] = h;
    lo[i] = f2bf(v - bf2f(h));
  }
}

// pad xp_w [4][40][256] -> xdp [4][64][256] (rows 40..63 zero)
__global__ __launch_bounds__(256) void k_padw(const float* __restrict__ xpw,
    float* __restrict__ xdp){
  int blk = blockIdx.x; int layer = blk >> 6, e = blk & 63;
  int tid = threadIdx.x;
  float v = 0.f;
  if (e < 40) v = xpw[((size_t)layer*40 + e)*256 + tid];
  xdp[((size_t)layer*64 + e)*256 + tid] = v;
}

// embed: 32-row tiles, W staged in LDS once per block. grid 256, blk 256.
__global__ __launch_bounds__(256) void k_embed(const float* __restrict__ x,
    const float* __restrict__ W, const float* __restrict__ bb, float* __restrict__ h,
    unsigned short* __restrict__ hhi, unsigned short* __restrict__ hlo){
  __shared__ float xsd[32*64];     // 8 KB
  __shared__ float Wl_[64*128];    // 32 KB
  const int tid = threadIdx.x;
  const int r0 = blockIdx.x << 5;
  #pragma unroll
  for (int p=0;p<2;p++){
    int q = tid + p*256;           // 512 f4 of x tile
    int r = q >> 4, c = (q & 15) << 2;
    *(float4*)&xsd[r*64 + c] = *(const float4*)(x + (size_t)(r0+r)*64 + c);
  }
  #pragma unroll
  for (int p=0;p<8;p++){
    int q = tid + p*256;           // 2048 f4 of W
    int r = q >> 5, c = (q & 31) << 2;
    *(float4*)&Wl_[r*128 + c] = *(const float4*)(W + (size_t)r*128 + c);
  }
  __syncthreads();
  const int e = tid & 127, rh = tid >> 7;
  const float bias = bb[e];
  for (int rr = rh*16; rr < rh*16+16; ++rr){
    float acc = bias;
    #pragma unroll
    for (int k=0;k<64;k++) acc = fmaf(xsd[rr*64 + k], Wl_[k*128 + e], acc);
    size_t idx = (size_t)(r0+rr)*128 + e;
    h[idx] = acc;
    unsigned short hb = f2bf(acc);
    hhi[idx] = hb;
    hlo[idx] = f2bf(acc - bf2f(hb));
  }
}

// C[M,N] = A[M,K]@W[N,K]^T via bf16x3 MFMA. Block = 4 waves 2x2.
// MT = m-frags per wave; block tile = (MT*32) x 64.
template<int MT>
__global__ __launch_bounds__(256) void k_mfma_bt(
    const unsigned short* __restrict__ Ahi, const unsigned short* __restrict__ Alo,
    const unsigned short* __restrict__ Whi, const unsigned short* __restrict__ Wlo,
    float* __restrict__ C, unsigned short* __restrict__ Chi, unsigned short* __restrict__ Clo,
    int M, int N, int K){
  const int tid = threadIdx.x;
  const int l = tid & 63, w = tid >> 6;
  const int wr = w >> 1, wc = w & 1;
  const int l15 = l & 15;
  const int ko = (l >> 4) << 3;          // k-offset 0/8/16/24 (same map for A and W)
  const int m0 = blockIdx.x * (MT*32);
  const int n0 = blockIdx.y << 6;
  const int arow = m0 + wr*(MT*16) + l15;
  const int wrow = n0 + wc*32 + l15;
  f32x4 acc[MT][2] = {};
  for (int kk = 0; kk < K; kk += 32){
    short8 ah[MT], al[MT], wh[2], wl[2];
    #pragma unroll
    for (int t=0;t<MT;t++){
      size_t off = (size_t)(arow + t*16)*K + kk + ko;
      ah[t] = *(const short8*)(Ahi + off);
      al[t] = *(const short8*)(Alo + off);
    }
    #pragma unroll
    for (int s=0;s<2;s++){
      size_t off = (size_t)(wrow + s*16)*K + kk + ko;
      wh[s] = *(const short8*)(Whi + off);
      wl[s] = *(const short8*)(Wlo + off);
    }
    #pragma unroll
    for (int t=0;t<MT;t++){
      #pragma unroll
      for (int s=0;s<2;s++){
        acc[t][s] = __builtin_amdgcn_mfma_f32_16x16x32_bf16(ah[t], wh[s], acc[t][s], 0,0,0);
        acc[t][s] = __builtin_amdgcn_mfma_f32_16x16x32_bf16(ah[t], wl[s], acc[t][s], 0,0,0);
        acc[t][s] = __builtin_amdgcn_mfma_f32_16x16x32_bf16(al[t], wh[s], acc[t][s], 0,0,0);
      }
    }
  }
  const int r0 = (l >> 4) << 2;          // C/D: col=lane&15, row=(lane>>4)*4+r
  #pragma unroll
  for (int t=0;t<MT;t++){
    #pragma unroll
    for (int s=0;s<2;s++){
      #pragma unroll
      for (int r=0;r<4;r++){
        int row = m0 + wr*(MT*16) + t*16 + r0 + r;
        int col = n0 + wc*32 + s*16 + l15;
        size_t idx = (size_t)row*N + col;
        float v = acc[t][s][r];
        if (C) C[idx] = v;
        if (Chi){
          unsigned short hb = f2bf(v);
          Chi[idx] = hb;
          Clo[idx] = f2bf(v - bf2f(hb));
        }
      }
    }
  }
}

// fused conv(silu) + x_proj GEMM + dt-proj(softplus) + B/C extraction.
// grid 512 (16-row tiles), blk 256.
__global__ __launch_bounds__(256) void k_mid(const float* __restrict__ xz,
    const float* __restrict__ cw, const float* __restrict__ cb,
    const float* __restrict__ xdp, const float* __restrict__ dtw,
    const float* __restrict__ dtb, float* __restrict__ u,
    float* __restrict__ dl, float* __restrict__ bc){
  __shared__ float xs[19*256];    // xz u-half rows l0-3..l0+15 (19.5 KB)
  __shared__ float ul[16*260];    // u tile, stride 260 vs bank conflicts (16.6 KB)
  __shared__ float Ws[32*68];     // W k-slab [k][n] (8.7 KB)
  __shared__ float xds[16*8];     // xd[:, :8] for dt-proj
  const int tid = threadIdx.x;
  const int r0 = blockIdx.x << 4;
  const int b = r0 >> 11, l0 = r0 & 2047;
  // per-thread params loaded early
  float4 cwv = *(const float4*)(cw + tid*4);
  float cbv = cb[tid];
  float4 dw0 = *(const float4*)(dtw + tid*8);
  float4 dw1 = *(const float4*)(dtw + tid*8 + 4);
  float dbv = dtb[tid];
  // stage xz u-half with 3-row causal halo
  for (int q = tid; q < 19*16; q += 256){
    int r = q >> 4, c4 = (q & 15) << 2;
    int lg = l0 - 3 + r;
    float4 v = make_float4(0.f,0.f,0.f,0.f);
    if (lg >= 0) v = *(const float4*)(xz + ((size_t)b*2048 + lg)*512 + c4);
    *(float4*)&xs[r*256 + c4] = v;
  }
  __syncthreads();
  // conv + silu -> ul (LDS) + u (global)
  #pragma unroll
  for (int rr=0;rr<16;rr++){
    float acc = cbv;
    acc = fmaf(xs[(rr+0)*256 + tid], cwv.x, acc);
    acc = fmaf(xs[(rr+1)*256 + tid], cwv.y, acc);
    acc = fmaf(xs[(rr+2)*256 + tid], cwv.z, acc);
    acc = fmaf(xs[(rr+3)*256 + tid], cwv.w, acc);
    float v = siluf(acc);
    ul[rr*260 + tid] = v;
    u[(size_t)(r0+rr)*256 + tid] = v;
  }
  __syncthreads();
  // xg: xd[16][64] = ul @ xdp^T. thread = (row = tid>>4, ng = tid&15)
  const int row = tid >> 4, ng = tid & 15;
  float a0=0.f,a1=0.f,a2=0.f,a3=0.f;
  for (int k0=0;k0<8;k0++){
    #pragma unroll
    for (int p=0;p<2;p++){
      int q = tid + p*256;
      int n = q >> 3, wc4 = (q & 7) << 2;
      float4 wv = *(const float4*)(xdp + (size_t)n*256 + k0*32 + wc4);
      Ws[(wc4+0)*68 + n]=wv.x; Ws[(wc4+1)*68 + n]=wv.y;
      Ws[(wc4+2)*68 + n]=wv.z; Ws[(wc4+3)*68 + n]=wv.w;
    }
    __syncthreads();
    #pragma unroll
    for (int k=0;k<32;k++){
      float a = ul[row*260 + k0*32 + k];
      float4 wv = *(const float4*)&Ws[k*68 + (ng<<2)];
      a0 = fmaf(a, wv.x, a0); a1 = fmaf(a, wv.y, a1);
      a2 = fmaf(a, wv.z, a2); a3 = fmaf(a, wv.w, a3);
    }
    __syncthreads();
  }
  if (ng < 2) *(float4*)&xds[row*8 + (ng<<2)] = make_float4(a0,a1,a2,a3);
  if (ng >= 2 && ng < 10)
    *(float4*)(bc + (size_t)(r0+row)*32 + ((ng-2)<<2)) = make_float4(a0,a1,a2,a3);
  __syncthreads();
  // dt-proj + softplus: d = tid, 16 rows
  #pragma unroll
  for (int rr=0;rr<16;rr++){
    float acc = dbv;
    acc = fmaf(xds[rr*8+0], dw0.x, acc); acc = fmaf(xds[rr*8+1], dw0.y, acc);
    acc = fmaf(xds[rr*8+2], dw0.z, acc); acc = fmaf(xds[rr*8+3], dw0.w, acc);
    acc = fmaf(xds[rr*8+4], dw1.x, acc); acc = fmaf(xds[rr*8+5], dw1.y, acc);
    acc = fmaf(xds[rr*8+6], dw1.z, acc); acc = fmaf(xds[rr*8+7], dw1.w, acc);
    dl[(size_t)(r0+rr)*256 + tid] = softplusf(acc);
  }
}

// ---------------- scan ----------------
__global__ __launch_bounds__(128) void k_scan_a2(const float* __restrict__ dlt,
    const float* __restrict__ u, const float* __restrict__ bc,
    const float* __restrict__ alog, float* __restrict__ sf, float* __restrict__ sd){
  __shared__ float ds_[TC2*32], us_[TC2*32], bs_[TC2*16];
  const int tid = threadIdx.x;
  const int c = blockIdx.x, dg = blockIdx.y, b = blockIdx.z;
  const size_t row0 = (size_t)b*Lq + (size_t)c*TC2;
  {
    const float* dbase = dlt + row0*256 + dg*32;
    const float* ubase = u   + row0*256 + dg*32;
    #pragma unroll
    for (int k=0;k<4;k++){
      int q = tid + k*128;
      int r = q >> 3, c4 = (q & 7) << 2;
      *(float4*)&ds_[r*32 + c4] = *(const float4*)(dbase + (size_t)r*256 + c4);
      *(float4*)&us_[r*32 + c4] = *(const float4*)(ubase + (size_t)r*256 + c4);
    }
    const float* bbase = bc + row0*32;
    #pragma unroll
    for (int k=0;k<2;k++){
      int q = tid + k*128;
      int r = q >> 2, c4 = (q & 3) << 2;
      *(float4*)&bs_[r*16 + c4] = *(const float4*)(bbase + (size_t)r*32 + c4);
    }
  }
  __syncthreads();
  const int lane = tid & 63, w = tid >> 6;
  const int dloc = w*16 + (lane & 15);
  const int nq = (lane >> 4) & 3;
  const int d = dg*32 + dloc;
  float4 al = *(const float4*)(alog + d*16 + nq*4);
  float Av0 = -expf(al.x), Av1 = -expf(al.y), Av2 = -expf(al.z), Av3 = -expf(al.w);
  float s0=0.f,s1=0.f,s2=0.f,s3=0.f, sdl=0.f;
  for (int t=0;t<TC2;t++){
    float de = ds_[t*32 + dloc];
    float uu = us_[t*32 + dloc];
    float du = de*uu;
    float4 Bv = *(const float4*)&bs_[t*16 + (nq<<2)];
    s0 = fmaf(expf(de*Av0), s0, du*Bv.x);
    s1 = fmaf(expf(de*Av1), s1, du*Bv.y);
    s2 = fmaf(expf(de*Av2), s2, du*Bv.z);
    s3 = fmaf(expf(de*Av3), s3, du*Bv.w);
    sdl += de;
  }
  size_t idx = ((size_t)b*NC2 + c)*256 + d;
  *(float4*)(sf + idx*16 + (nq<<2)) = make_float4(s0,s1,s2,s3);
  if (nq==0) sd[idx] = sdl;
}

// combine chunk aggregates -> exclusive init per chunk; aggregates preloaded to regs
__global__ __launch_bounds__(256) void k_scan_b3(const float* __restrict__ sf,
    const float* __restrict__ sd, const float* __restrict__ alog, float* __restrict__ si){
  int b = blockIdx.x >> 4, dg = blockIdx.x & 15;
  int tid = threadIdx.x; int n = tid & 15, dl = tid >> 4; int d = dg*16 + dl;
  float Av = -expf(alog[d*16+n]);
  float sfv[NC2], sdv[NC2];
  #pragma unroll
  for (int c=0;c<NC2;c++){
    size_t idx = ((size_t)b*NC2 + c)*256 + d;
    sfv[c] = sf[idx*16+n];
    sdv[c] = sd[idx];
  }
  float s = 0.f;
  #pragma unroll
  for (int c=0;c<NC2;c++){
    size_t idx = ((size_t)b*NC2 + c)*256 + d;
    si[idx*16+n] = s;
    s = sfv[c] + expf(Av * sdv[c]) * s;
  }
}

// scan pass C: fused epilogue y=(sum_n sC + uD)*silu(z), emitted as bf16 hi/lo
__global__ __launch_bounds__(128) void k_scan_c2(const float* __restrict__ dlt,
    const float* __restrict__ u, const float* __restrict__ bc,
    const float* __restrict__ xz, const float* __restrict__ si,
    const float* __restrict__ alog, const float* __restrict__ dsk,
    unsigned short* __restrict__ yhi, unsigned short* __restrict__ ylo){
  __shared__ float ds_[TC2*32], us_[TC2*32], bcs_[TC2*32], zs_[TC2*32], ys_[TC2*32];
  const int tid = threadIdx.x;
  const int c = blockIdx.x, dg = blockIdx.y, b = blockIdx.z;
  const size_t row0 = (size_t)b*Lq + (size_t)c*TC2;
  {
    const float* dbase = dlt + row0*256 + dg*32;
    const float* ubase = u   + row0*256 + dg*32;
    const float* zbase = xz  + row0*512 + 256 + dg*32;
    const float* bbase = bc  + row0*32;
    #pragma unroll
    for (int k=0;k<4;k++){
      int q = tid + k*128;
      int r = q >> 3, c4 = (q & 7) << 2;
      *(float4*)&ds_[r*32 + c4]  = *(const float4*)(dbase + (size_t)r*256 + c4);
      *(float4*)&us_[r*32 + c4]  = *(const float4*)(ubase + (size_t)r*256 + c4);
      *(float4*)&zs_[r*32 + c4]  = *(const float4*)(zbase + (size_t)r*512 + c4);
      *(float4*)&bcs_[r*32 + c4] = *(const float4*)(bbase + (size_t)r*32  + c4);
    }
  }
  __syncthreads();
  const int lane = tid & 63, w = tid >> 6;
  const int dloc = w*16 + (lane & 15);
  const int nq = (lane >> 4) & 3;
  const int d = dg*32 + dloc;
  float4 al = *(const float4*)(alog + d*16 + (nq<<2));
  float Av0 = -expf(al.x), Av1 = -expf(al.y), Av2 = -expf(al.z), Av3 = -expf(al.w);
  float Dv = dsk[d];
  size_t idx = ((size_t)b*NC2 + c)*256 + d;
  float4 sv = *(const float4*)(si + idx*16 + (nq<<2));
  float s0 = sv.x, s1 = sv.y, s2 = sv.z, s3 = sv.w;
  for (int t=0;t<TC2;t++){
    float de = ds_[t*32 + dloc];
    float uu = us_[t*32 + dloc];
    float du = de*uu;
    float4 Bv = *(const float4*)&bcs_[t*32 + (nq<<2)];
    float4 Cv = *(const float4*)&bcs_[t*32 + 16 + (nq<<2)];
    s0 = fmaf(expf(de*Av0), s0, du*Bv.x);
    s1 = fmaf(expf(de*Av1), s1, du*Bv.y);
    s2 = fmaf(expf(de*Av2), s2, du*Bv.z);
    s3 = fmaf(expf(de*Av3), s3, du*Bv.w);
    float py = s0*Cv.x + s1*Cv.y + s2*Cv.z + s3*Cv.w;
    py += __shfl_xor(py, 16);
    py += __shfl_xor(py, 32);
    if (nq==0){
      float zz = zs_[t*32 + dloc];
      ys_[t*32 + dloc] = fmaf(uu, Dv, py) * siluf(zz);
    }
  }
  __syncthreads();
  {
    unsigned short* yh = yhi + row0*256 + dg*32;
    unsigned short* yl = ylo + row0*256 + dg*32;
    #pragma unroll
    for (int k=0;k<4;k++){
      int q = tid + k*128;
      int r = q >> 3, c4 = (q & 7) << 2;
      float4 v = *(const float4*)&ys_[r*32 + c4];
      ushort4 h4, l4;
      h4.x = f2bf(v.x); l4.x = f2bf(v.x - bf2f(h4.x));
      h4.y = f2bf(v.y); l4.y = f2bf(v.y - bf2f(h4.y));
      h4.z = f2bf(v.z); l4.z = f2bf(v.z - bf2f(h4.z));
      h4.w = f2bf(v.w); l4.w = f2bf(v.w - bf2f(h4.w));
      *(ushort4*)(yh + (size_t)r*256 + c4) = h4;
      *(ushort4*)(yl + (size_t)r*256 + c4) = l4;
    }
  }
}

// pool stage 1: per (b, 128-row group) partial sums
__global__ __launch_bounds__(256) void k_pool1(const float* __restrict__ h,
    float* __restrict__ part){
  int b = blockIdx.x >> 4, g = blockIdx.x & 15;
  int tid = threadIdx.x;
  int e = tid & 127, st = tid >> 7;
  float s = 0.f;
  int lbase = g*128 + st*64;
  for (int l = lbase; l < lbase+64; ++l) s += h[((size_t)b*2048 + l)*128 + e];
  part[((size_t)(b*16+g)*2 + st)*128 + e] = s;
}
// pool stage 2: reduce partials + latent GEMV
__global__ __launch_bounds__(128) void k_pool2(const float* __restrict__ part,
    const float* __restrict__ Wl, const float* __restrict__ bl_, float* __restrict__ out){
  int b = blockIdx.x; int e = threadIdx.x;
  __shared__ float pooled[128];
  float tot = 0.f;
  #pragma unroll
  for (int j=0;j<32;j++) tot += part[((size_t)b*32 + j)*128 + e];
  pooled[e] = tot * (1.f/2048.f);
  __syncthreads();
  float acc = bl_[e];
  for (int k=0;k<128;k++) acc = fmaf(pooled[k], Wl[k*128 + e], acc);
  out[b*128 + e] = acc;
}

extern "C" void kernel_launch(void* const* d_in, const int* in_sizes, int n_in,
                              void* d_out, int out_size, void* d_ws, size_t ws_size,
                              hipStream_t stream){
  const float* x    = (const float*)d_in[0];
  const float* Wem  = (const float*)d_in[1];
  const float* bem  = (const float*)d_in[2];
  const float* inw  = (const float*)d_in[3];
  const float* cw   = (const float*)d_in[4];
  const float* cb   = (const float*)d_in[5];
  const float* xpw  = (const float*)d_in[6];
  const float* dtw  = (const float*)d_in[7];
  const float* dtb  = (const float*)d_in[8];
  const float* alog = (const float*)d_in[9];
  const float* dsk  = (const float*)d_in[10];
  const float* outw = (const float*)d_in[11];
  const float* Wl   = (const float*)d_in[12];
  const float* bl_  = (const float*)d_in[13];
  float* out = (float*)d_out;

  float* p  = (float*)d_ws;
  float* h  = p;  p += (size_t)BLq*128;
  float* xz = p;  p += (size_t)BLq*512;
  float* u  = p;  p += (size_t)BLq*256;
  float* dl = p;  p += (size_t)BLq*256;
  float* bc = p;  p += (size_t)BLq*32;
  float* sf = p;  p += (size_t)Bq*NC2*256*16;
  float* sd = p;  p += (size_t)Bq*NC2*256;
  float* si = p;  p += (size_t)Bq*NC2*256*16;
  float* xdp= p;  p += (size_t)4*64*256;
  float* part=p;  p += (size_t)Bq*32*128;
  unsigned short* q = (unsigned short*)p;
  unsigned short* wihi = q; q += (size_t)4*512*128;
  unsigned short* wilo = q; q += (size_t)4*512*128;
  unsigned short* wohi = q; q += (size_t)4*128*256;
  unsigned short* wolo = q; q += (size_t)4*128*256;
  unsigned short* hhi  = q; q += (size_t)BLq*128;
  unsigned short* hlo  = q; q += (size_t)BLq*128;
  unsigned short* yhi  = q; q += (size_t)BLq*256;
  unsigned short* ylo  = q; q += (size_t)BLq*256;

  k_split<<<1024, 256, 0, stream>>>(inw, wihi, wilo, 4*512*128);
  k_split<<<512, 256, 0, stream>>>(outw, wohi, wolo, 4*128*256);
  k_padw<<<256, 256, 0, stream>>>(xpw, xdp);
  k_embed<<<256, 256, 0, stream>>>(x, Wem, bem, h, hhi, hlo);
  for (int layer=0; layer<4; ++layer){
    k_mfma_bt<4><<<dim3(64,8), 256, 0, stream>>>(hhi, hlo,
        wihi + (size_t)layer*512*128, wilo + (size_t)layer*512*128,
        xz, nullptr, nullptr, BLq, 512, 128);
    k_mid<<<512, 256, 0, stream>>>(xz, cw + (size_t)layer*256*4, cb + (size_t)layer*256,
        xdp + (size_t)layer*64*256, dtw + (size_t)layer*256*8, dtb + (size_t)layer*256,
        u, dl, bc);
    k_scan_a2<<<dim3(NC2,8,Bq), 128, 0, stream>>>(dl, u, bc, alog + (size_t)layer*4096, sf, sd);
    k_scan_b3<<<64, 256, 0, stream>>>(sf, sd, alog + (size_t)layer*4096, si);
    k_scan_c2<<<dim3(NC2,8,Bq), 128, 0, stream>>>(dl, u, bc, xz, si, alog + (size_t)layer*4096,
                                                  dsk + (size_t)layer*256, yhi, ylo);
    k_mfma_bt<2><<<dim3(128,2), 256, 0, stream>>>(yhi, ylo,
        wohi + (size_t)layer*128*256, wolo + (size_t)layer*128*256,
        (layer==3)? h : nullptr, hhi, hlo, BLq, 128, 256);
  }
  k_pool1<<<64, 256, 0, stream>>>(h, part);
  k_pool2<<<Bq, 128, 0, stream>>>(part, Wl, bl_, out);
}